// Round 7
// baseline (2438.830 us; speedup 1.0000x reference)
//
#include <hip/hip_runtime.h>

typedef _Float16 f16;
typedef _Float16 f16x2 __attribute__((ext_vector_type(2)));
typedef _Float16 f16x8 __attribute__((ext_vector_type(8)));
typedef float    f32x4 __attribute__((ext_vector_type(4)));
typedef unsigned int u32x4 __attribute__((ext_vector_type(4)));

// ---------- helpers ----------
__device__ __forceinline__ float dot2u(unsigned a, unsigned b, float c){
  return __builtin_amdgcn_fdot2(__builtin_bit_cast(f16x2, a),
                                __builtin_bit_cast(f16x2, b), c, false);
}
__device__ __forceinline__ float sigm(float x){ return 1.0f/(1.0f+__expf(-x)); }
__device__ __forceinline__ float tanh_(float x){
  x = fminf(fmaxf(x, -20.f), 20.f);
  return 1.0f - 2.0f/(__expf(2.0f*x)+1.0f);
}

// Barrier that does NOT drain vmcnt (in-loop cross-thread traffic is LDS-only).
__device__ __forceinline__ void bar_lgkm(){
  asm volatile("s_waitcnt lgkmcnt(0)\n\ts_barrier" ::: "memory");
}

// manual OCP e4m3fn encode (RNE) — weight-pack prep
__device__ __forceinline__ unsigned char enc_e4m3(float x){
  unsigned bits = __builtin_bit_cast(unsigned, x);
  unsigned s = (bits >> 24) & 0x80u;
  float ax = __builtin_bit_cast(float, bits & 0x7fffffffu);
  if (ax < 9.765625e-4f) return (unsigned char)s;
  if (ax >= 448.0f) return (unsigned char)(s | 0x7e);
  int e; (void)frexpf(ax, &e);
  int E = e - 1;
  if (E < -6){
    int qi = (int)rintf(ldexpf(ax, 9));
    if (qi >= 8) return (unsigned char)(s | 0x08);
    return (unsigned char)(s | qi);
  }
  int qi = (int)rintf(ldexpf(ax, 3 - E));
  if (qi >= 16){ E++; qi = 8; if (E > 8) return (unsigned char)(s | 0x7e); }
  return (unsigned char)(s | (unsigned)((E + 7) << 3) | (unsigned)(qi - 8));
}

__device__ __forceinline__ unsigned char enc_e4m3_fast(float x){
#if __has_builtin(__builtin_amdgcn_cvt_pk_fp8_f32)
  int pk = __builtin_amdgcn_cvt_pk_fp8_f32(x, x, 0, false);
  return (unsigned char)(pk & 0xff);
#else
  return enc_e4m3(x);
#endif
}

// ---------- K0: fp32 -> f16 convert (8 elems/thread) ----------
__global__ void k_cvt(const float* __restrict__ src, f16* __restrict__ dst, int n){
  int i = (blockIdx.x*256 + threadIdx.x)*8;
  if (i >= n) return;
  float4 a = *(const float4*)(src + i);
  float4 b = *(const float4*)(src + i + 4);
  f16x8 o;
  o[0]=(f16)a.x; o[1]=(f16)a.y; o[2]=(f16)a.z; o[3]=(f16)a.w;
  o[4]=(f16)b.x; o[5]=(f16)b.y; o[6]=(f16)b.z; o[7]=(f16)b.w;
  *(f16x8*)(dst+i) = o;
}

// ---------- K0c: pack W_hh into fp8 MFMA A-frags with gate-interleaved row perm ----
// Entry idx = dir*32768 + wv*4096 + rt*512 + kt*64 + lane (8 bytes each).
// A-frag: lane holds A[row_in_tile = lane&15][k = kt*32 + (lane>>4)*8 + j].
// Row permutation: row_in_tile i of tile (wv,rt) = (unit u = wv*32 + (i>>2)*8 + rt,
// gate g = i&3)  ->  W_hh source row = g*256 + u.  Weights prescaled x16 e4m3.
__global__ void k_wpack6(const float* __restrict__ whf, const float* __restrict__ whb,
                         unsigned int* __restrict__ wf){
  int idx = blockIdx.x*256 + threadIdx.x;    // 0..65535
  int lane = idx & 63;
  int kt   = (idx >> 6) & 7;
  int rt   = (idx >> 9) & 7;
  int wv   = (idx >> 12) & 7;
  int dir  = (idx >> 15) & 1;
  const float* w = dir ? whb : whf;
  int i  = lane & 15;
  int u  = wv*32 + (i >> 2)*8 + rt;
  int g  = i & 3;
  int k0 = kt*32 + (lane >> 4)*8;
  const float* row = w + (size_t)(g*256 + u)*256 + k0;
  unsigned char by[8];
  #pragma unroll
  for (int j=0;j<8;j++) by[j] = enc_e4m3(row[j] * 16.0f);
  unsigned lo = (unsigned)by[0] | ((unsigned)by[1]<<8) | ((unsigned)by[2]<<16) | ((unsigned)by[3]<<24);
  unsigned hi = (unsigned)by[4] | ((unsigned)by[5]<<8) | ((unsigned)by[6]<<16) | ((unsigned)by[7]<<24);
  wf[(size_t)idx*2]   = lo;
  wf[(size_t)idx*2+1] = hi;
}

// ---------- K1: gx = X(32768x768) @ Wcat(2048x768)^T + bias  (f16 out) ----------
__global__ __launch_bounds__(256) void k_gemm(const f16* __restrict__ A,
                                              const f16* __restrict__ Bw,
                                              const float* __restrict__ bf_,
                                              const float* __restrict__ bb_,
                                              f16* __restrict__ C){
  __shared__ alignas(16) f16 As[128][64];
  __shared__ alignas(16) f16 Bs[128][64];
  int bid = blockIdx.x;
  int bm = bid >> 4, bn = bid & 15;
  int tid = threadIdx.x;
  int w = tid >> 6, l = tid & 63;
  int wm = w >> 1, wn = w & 1;
  f32x4 acc[4][4] = {};
  int srow = tid >> 3;
  int scol = (tid & 7)*8;
  const f16* Ag = A  + (size_t)(bm*128)*768 + scol;
  const f16* Bg = Bw + (size_t)(bn*128)*768 + scol;
  int fr = l & 15, kg = l >> 4;
  for (int k0 = 0; k0 < 768; k0 += 64){
    #pragma unroll
    for (int q=0;q<4;q++){
      int rr = srow + 32*q;
      u32x4 av = *(const u32x4*)(Ag + rr*768 + k0);
      u32x4 bv = *(const u32x4*)(Bg + rr*768 + k0);
      *(u32x4*)&As[rr][scol] = av;
      *(u32x4*)&Bs[rr][scol] = bv;
    }
    __syncthreads();
    #pragma unroll
    for (int ks=0; ks<2; ks++){
      f16x8 af[4], bf[4];
      #pragma unroll
      for (int mi=0;mi<4;mi++) af[mi] = *(const f16x8*)&As[wm*64+mi*16+fr][ks*32+kg*8];
      #pragma unroll
      for (int ni=0;ni<4;ni++) bf[ni] = *(const f16x8*)&Bs[wn*64+ni*16+fr][ks*32+kg*8];
      #pragma unroll
      for (int mi=0;mi<4;mi++)
        #pragma unroll
        for (int ni=0;ni<4;ni++)
          acc[mi][ni] = __builtin_amdgcn_mfma_f32_16x16x32_f16(af[mi], bf[ni], acc[mi][ni], 0,0,0);
    }
    __syncthreads();
  }
  int fq = l >> 4;
  #pragma unroll
  for (int ni=0;ni<4;ni++){
    int nc = bn*128 + wn*64 + ni*16 + fr;
    float bv = (nc < 1024) ? bf_[nc] : bb_[nc - 1024];
    #pragma unroll
    for (int mi=0;mi<4;mi++){
      int mrow = bm*128 + wm*64 + mi*16 + fq*4;
      #pragma unroll
      for (int r=0;r<4;r++)
        C[(size_t)(mrow+r)*2048 + nc] = (f16)(acc[mi][ni][r] + bv);
    }
  }
}

// ---------- K2: recurrence, 16 chains/block via fp8 MFMA (no wasted columns) ----
// 8 blocks: dir = bid&1, chain group bg = bid>>1 covers batches bg*16..bg*16+15.
// 512 thr = 8 waves; wave wv owns permuted W rows (128) = units wv*32..+31 x 4 gates.
// Lane l: chain ch = l&15, qc = l>>4; acc[rt][g] = gate g pre-act of unit
// u = wv*32 + qc*8 + rt, chain ch  ->  cell update fully lane-local.
// B-frags: 8 ds_read_b64 from 4KB [k-octet][chain] h-buffer; h-publish 1 ds_write_b64.
__global__ __launch_bounds__(512,2) void k_rnn(const unsigned int* __restrict__ wfrag,
            const f16* __restrict__ gx, f16* __restrict__ Hc){
  __shared__ unsigned long long lh2[2][32][16];   // 8 KB: [buf][k-octet][chain]
  int bid = blockIdx.x;
  int bg = bid >> 1, dir = bid & 1;
  int tid = threadIdx.x;
  int wv = tid >> 6, lane = tid & 63;
  int qc = lane >> 4, ch = lane & 15;
  int b  = bg*16 + ch;
  int U0 = wv*32 + qc*8;
  const long* wfp = (const long*)wfrag + (size_t)(dir*8 + wv)*4096 + lane;
  long a[64];                                     // A-frags, 128 VGPRs
  #pragma unroll
  for (int i=0;i<64;i++) a[i] = wfp[(size_t)i*64];
  ((unsigned long long*)lh2)[tid] = 0ULL;         // zero buffer 0 (512 entries)
  float c[8];
  #pragma unroll
  for (int r=0;r<8;r++) c[r] = 0.0f;
  const f16* gxb = gx + (size_t)b*512*2048 + dir*1024 + U0;
  f16* Hcb = Hc + (size_t)b*512*512 + dir*256 + U0;
  __syncthreads();
  for (int t=0; t<512; t++){
    int s = dir ? (511-t) : t;
    int cur = t & 1;
    long hb[8];
    #pragma unroll
    for (int kt=0; kt<8; kt++) hb[kt] = (long)lh2[cur][kt*4 + qc][ch];
    // issue this step's gx loads early; consumed after the MFMA burst (~2500 cyc)
    const f16* gp = gxb + (size_t)s*2048;
    f16 gcur[32];
    #pragma unroll
    for (int g2=0; g2<4; g2++)
      #pragma unroll
      for (int rt=0; rt<8; rt++) gcur[g2*8+rt] = gp[g2*256 + rt];
    f32x4 ac[8];
    #pragma unroll
    for (int rt=0; rt<8; rt++) ac[rt] = (f32x4){0.f,0.f,0.f,0.f};
    #pragma unroll
    for (int kt=0; kt<8; kt++){
      #pragma unroll
      for (int rt=0; rt<8; rt++)
        ac[rt] = __builtin_amdgcn_mfma_f32_16x16x32_fp8_fp8(a[rt*8+kt], hb[kt], ac[rt], 0,0,0);
    }
    f16x8 hv;
    unsigned long long hpack = 0ULL;
    #pragma unroll
    for (int rt=0; rt<8; rt++){
      float p0 = ac[rt][0]*0.0625f + (float)gcur[ 0+rt];
      float p1 = ac[rt][1]*0.0625f + (float)gcur[ 8+rt];
      float p2 = ac[rt][2]*0.0625f + (float)gcur[16+rt];
      float p3 = ac[rt][3]*0.0625f + (float)gcur[24+rt];
      float ig = sigm(p0), fg = sigm(p1);
      float gg = tanh_(p2), og = sigm(p3);
      c[rt] = fg*c[rt] + ig*gg;
      float h = og*tanh_(c[rt]);
      hv[rt] = (f16)h;
      hpack |= ((unsigned long long)enc_e4m3_fast(h)) << (8*rt);
    }
    *(f16x8*)(Hcb + (size_t)s*512) = hv;          // 16B store, 8 contiguous units
    lh2[cur^1][wv*4 + qc][ch] = hpack;            // publish 8 h-bytes
    bar_lgkm();
  }
}

// ---------- K3: emissions e[m][k] = Hcat[m] . Wproj[k] + b_proj[k]  (wave per row) ----------
__global__ __launch_bounds__(256) void k_emis(const f16* __restrict__ Hc,
                 const f16* __restrict__ Wp, const float* __restrict__ bp,
                 float* __restrict__ e){
  int w = threadIdx.x >> 6, l = threadIdx.x & 63;
  int m = blockIdx.x*4 + w;
  f16x8 hv = *(const f16x8*)(Hc + (size_t)m*512 + l*8);
  u32x4 hu = __builtin_bit_cast(u32x4, hv);
  #pragma unroll
  for (int k=0;k<9;k++){
    f16x8 wv = *(const f16x8*)(Wp + k*512 + l*8);
    u32x4 wu = __builtin_bit_cast(u32x4, wv);
    float p = 0.f;
    #pragma unroll
    for (int q=0;q<4;q++) p = dot2u(hu[q], wu[q], p);
    #pragma unroll
    for (int off=32; off; off>>=1) p += __shfl_xor(p, off);
    if (l == k) e[(size_t)m*9 + k] = p + bp[k];
  }
}

// ---------- K4: CRF negative-llh pieces per batch (1 wave per batch) ----------
__global__ void k_crf(const float* __restrict__ e, const int* __restrict__ tags,
                      const int* __restrict__ mask, const float* __restrict__ st,
                      const float* __restrict__ en, const float* __restrict__ tr,
                      float* __restrict__ llh){
  int b = blockIdx.x;
  int l = threadIdx.x;
  int j = (l < 9) ? l : 0;
  float Tc[9];
  #pragma unroll
  for (int i=0;i<9;i++) Tc[i] = tr[i*9 + j];
  const float* eb = e + (size_t)b*512*9;
  const int* tb = tags + b*512;
  const int* mb = mask + b*512;
  float a = st[j] + eb[j];
  int t0 = tb[0];
  float num = st[t0] + eb[t0];
  int prev = t0;
  int cnt = (mb[0] != 0) ? 1 : 0;
  for (int s=1; s<512; s++){
    float ej = eb[s*9 + j];
    float vi[9];
    #pragma unroll
    for (int i=0;i<9;i++) vi[i] = __shfl(a, i) + Tc[i];
    float mx = vi[0];
    #pragma unroll
    for (int i=1;i<9;i++) mx = fmaxf(mx, vi[i]);
    float ssum = 0.f;
    #pragma unroll
    for (int i=0;i<9;i++) ssum += expf(vi[i]-mx);
    float anew = ej + mx + logf(ssum);
    int mt = mb[s];
    a = (mt != 0) ? anew : a;
    int tg = tb[s];
    num += (float)mt * (tr[prev*9+tg] + eb[s*9+tg]);
    prev = tg;
    cnt += (mt != 0) ? 1 : 0;
  }
  float av[9];
  #pragma unroll
  for (int i=0;i<9;i++) av[i] = __shfl(a, i) + en[i];
  float mx = av[0];
  #pragma unroll
  for (int i=1;i<9;i++) mx = fmaxf(mx, av[i]);
  float ssum = 0.f;
  #pragma unroll
  for (int i=0;i<9;i++) ssum += expf(av[i]-mx);
  float logZ = mx + logf(ssum);
  if (l == 0){
    int lastt = tb[cnt-1];
    llh[b] = (num + en[lastt]) - logZ;
  }
}

// ---------- K5: final reduce ----------
__global__ void k_red(const float* __restrict__ llh, float* __restrict__ out){
  if (threadIdx.x == 0){
    float s = 0.f;
    for (int i=0;i<64;i++) s += llh[i];
    out[0] = -s / 64.0f;
  }
}

extern "C" void kernel_launch(void* const* d_in, const int* in_sizes, int n_in,
                              void* d_out, int out_size, void* d_ws, size_t ws_size,
                              hipStream_t stream){
  const float* emb  = (const float*)d_in[0];
  const int*   tags = (const int*)d_in[1];
  const int*   mask = (const int*)d_in[2];
  const float* wihf = (const float*)d_in[3];
  const float* whhf = (const float*)d_in[4];
  const float* bfp  = (const float*)d_in[5];
  const float* wihb = (const float*)d_in[6];
  const float* whhb = (const float*)d_in[7];
  const float* bbp  = (const float*)d_in[8];
  const float* wprj = (const float*)d_in[9];
  const float* bprj = (const float*)d_in[10];
  const float* st   = (const float*)d_in[11];
  const float* en   = (const float*)d_in[12];
  const float* tr   = (const float*)d_in[13];

  char* ws = (char*)d_ws;
  f16*   Xf    = (f16*)(ws + 0);                 // 50,331,648 B (aliased by Hc later)
  f16*   Wcat  = (f16*)(ws + 50331648);          //  3,145,728 B
  unsigned int* Wpack = (unsigned int*)(ws + 53477376);  // 524,288 B used
  f16*   Wpj   = (f16*)(ws + 54525952);          //      9,216 B
  f16*   gx    = (f16*)(ws + 54535168);          // 134,217,728 B
  float* e     = (float*)(ws + 188752896);       //  1,179,648 B
  float* llh   = (float*)(ws + 189932544);       //        256 B
  f16*   Hc    = Xf;   // safe alias: X only read by k_gemm, which precedes k_rnn

  hipLaunchKernelGGL(k_cvt,    dim3(12288), dim3(256), 0, stream, emb,  Xf, 25165824);
  hipLaunchKernelGGL(k_cvt,    dim3(384),   dim3(256), 0, stream, wihf, Wcat,          786432);
  hipLaunchKernelGGL(k_cvt,    dim3(384),   dim3(256), 0, stream, wihb, Wcat + 786432, 786432);
  hipLaunchKernelGGL(k_cvt,    dim3(3),     dim3(256), 0, stream, wprj, Wpj, 4608);
  hipLaunchKernelGGL(k_wpack6, dim3(256),   dim3(256), 0, stream, whhf, whhb, Wpack);
  hipLaunchKernelGGL(k_gemm,   dim3(4096),  dim3(256), 0, stream, Xf, Wcat, bfp, bbp, gx);
  hipLaunchKernelGGL(k_rnn,    dim3(8),     dim3(512), 0, stream, Wpack, gx, Hc);
  hipLaunchKernelGGL(k_emis,   dim3(8192),  dim3(256), 0, stream, Hc, Wpj, bprj, e);
  hipLaunchKernelGGL(k_crf,    dim3(64),    dim3(64),  0, stream, e, tags, mask, st, en, tr, llh);
  hipLaunchKernelGGL(k_red,    dim3(1),     dim3(64),  0, stream, llh, (float*)d_out);
}

// Round 8
// 2356.235 us; speedup vs baseline: 1.0351x; 1.0351x over previous
//
#include <hip/hip_runtime.h>

typedef _Float16 f16;
typedef _Float16 f16x2 __attribute__((ext_vector_type(2)));
typedef _Float16 f16x8 __attribute__((ext_vector_type(8)));
typedef float    f32x4 __attribute__((ext_vector_type(4)));
typedef int      i32x4 __attribute__((ext_vector_type(4)));
typedef unsigned int u32x4 __attribute__((ext_vector_type(4)));

// ---------- helpers ----------
__device__ __forceinline__ float dot2u(unsigned a, unsigned b, float c){
  return __builtin_amdgcn_fdot2(__builtin_bit_cast(f16x2, a),
                                __builtin_bit_cast(f16x2, b), c, false);
}
__device__ __forceinline__ float sigm(float x){ return 1.0f/(1.0f+__expf(-x)); }
__device__ __forceinline__ float tanh_(float x){
  x = fminf(fmaxf(x, -20.f), 20.f);
  return 1.0f - 2.0f/(__expf(2.0f*x)+1.0f);
}

// Barrier that does NOT drain vmcnt (in-loop cross-thread traffic is LDS-only).
__device__ __forceinline__ void bar_lgkm(){
  asm volatile("s_waitcnt lgkmcnt(0)\n\ts_barrier" ::: "memory");
}

// ---------- K0: fp32 -> f16 convert (8 elems/thread) ----------
__global__ void k_cvt(const float* __restrict__ src, f16* __restrict__ dst, int n){
  int i = (blockIdx.x*256 + threadIdx.x)*8;
  if (i >= n) return;
  float4 a = *(const float4*)(src + i);
  float4 b = *(const float4*)(src + i + 4);
  f16x8 o;
  o[0]=(f16)a.x; o[1]=(f16)a.y; o[2]=(f16)a.z; o[3]=(f16)a.w;
  o[4]=(f16)b.x; o[5]=(f16)b.y; o[6]=(f16)b.z; o[7]=(f16)b.w;
  *(f16x8*)(dst+i) = o;
}

// ---------- K0c: pack W_hh into i8 MFMA A-frags (16x16x64), gate-interleaved perm ----
// Entry idx = dir*16384 + wv*2048 + rt*256 + kt*64 + lane  (16 bytes each).
// A-frag layout (K=64, 4 VGPRs): lane holds A[row = lane&15][k = kt*64 + (lane>>4)*16 + j].
// Row perm: row_in_tile i of tile (wv,rt): unit u = wv*32 + (i>>2)*8 + rt, gate = i&3
//   -> W_hh source row = gate*256 + u.  Weights scaled x2048, clamped to [-127,127].
__global__ void k_wpack7(const float* __restrict__ whf, const float* __restrict__ whb,
                         u32x4* __restrict__ wf){
  int idx = blockIdx.x*256 + threadIdx.x;    // 0..32767
  int lane = idx & 63;
  int kt   = (idx >> 6) & 3;
  int rt   = (idx >> 8) & 7;
  int wv   = (idx >> 11) & 7;
  int dir  = (idx >> 14) & 1;
  const float* w = dir ? whb : whf;
  int i  = lane & 15;
  int u  = wv*32 + (i >> 2)*8 + rt;
  int g  = i & 3;
  int k0 = kt*64 + (lane >> 4)*16;
  const float* row = w + (size_t)(g*256 + u)*256 + k0;
  u32x4 v = {0,0,0,0};
  #pragma unroll
  for (int j=0;j<16;j++){
    int q = (int)rintf(row[j] * 2048.0f);
    q = q > 127 ? 127 : (q < -127 ? -127 : q);
    v[j>>2] |= ((unsigned)(unsigned char)(signed char)q) << ((j&3)*8);
  }
  wf[idx] = v;
}

// ---------- K1: gxp = X @ Wcat^T + bias, written in k_rnn-native layout ----------
// gxp element index: ((bg*2+dir)*512 + s)*16384 + wv*2048 + qc*512 + ch*32 + g2*8 + rt
// where (b = bg*16+ch, s) = X row, ncol = dir*1024 + g2*256 + (wv*32 + qc*8 + rt).
__global__ __launch_bounds__(256) void k_gemm(const f16* __restrict__ A,
                                              const f16* __restrict__ Bw,
                                              const float* __restrict__ bf_,
                                              const float* __restrict__ bb_,
                                              f16* __restrict__ C){
  __shared__ alignas(16) f16 As[128][64];
  __shared__ alignas(16) f16 Bs[128][64];
  int bid = blockIdx.x;
  int bm = bid >> 4, bn = bid & 15;
  int tid = threadIdx.x;
  int w = tid >> 6, l = tid & 63;
  int wm = w >> 1, wn = w & 1;
  f32x4 acc[4][4] = {};
  int srow = tid >> 3;
  int scol = (tid & 7)*8;
  const f16* Ag = A  + (size_t)(bm*128)*768 + scol;
  const f16* Bg = Bw + (size_t)(bn*128)*768 + scol;
  int fr = l & 15, kg = l >> 4;
  for (int k0 = 0; k0 < 768; k0 += 64){
    #pragma unroll
    for (int q=0;q<4;q++){
      int rr = srow + 32*q;
      u32x4 av = *(const u32x4*)(Ag + rr*768 + k0);
      u32x4 bv = *(const u32x4*)(Bg + rr*768 + k0);
      *(u32x4*)&As[rr][scol] = av;
      *(u32x4*)&Bs[rr][scol] = bv;
    }
    __syncthreads();
    #pragma unroll
    for (int ks=0; ks<2; ks++){
      f16x8 af[4], bf[4];
      #pragma unroll
      for (int mi=0;mi<4;mi++) af[mi] = *(const f16x8*)&As[wm*64+mi*16+fr][ks*32+kg*8];
      #pragma unroll
      for (int ni=0;ni<4;ni++) bf[ni] = *(const f16x8*)&Bs[wn*64+ni*16+fr][ks*32+kg*8];
      #pragma unroll
      for (int mi=0;mi<4;mi++)
        #pragma unroll
        for (int ni=0;ni<4;ni++)
          acc[mi][ni] = __builtin_amdgcn_mfma_f32_16x16x32_f16(af[mi], bf[ni], acc[mi][ni], 0,0,0);
    }
    __syncthreads();
  }
  int fq = l >> 4;
  #pragma unroll
  for (int ni=0;ni<4;ni++){
    int nc = bn*128 + wn*64 + ni*16 + fr;
    int dirc = nc >> 10, tt = nc & 1023;
    int g2 = tt >> 8, u = tt & 255;
    int colpart = (u>>5)*2048 + ((u>>3)&3)*512 + g2*8 + (u&7);
    float bv = (nc < 1024) ? bf_[nc] : bb_[nc - 1024];
    #pragma unroll
    for (int mi=0;mi<4;mi++){
      int mrow = bm*128 + wm*64 + mi*16 + fq*4;
      #pragma unroll
      for (int r=0;r<4;r++){
        int m = mrow + r;
        int b2 = m >> 9, s = m & 511;
        size_t q = ((size_t)((b2>>4)*1024 + dirc*512 + s))*16384
                 + (size_t)colpart + (size_t)(b2&15)*32;
        C[q] = (f16)(acc[mi][ni][r] + bv);
      }
    }
  }
}

// ---------- K2: recurrence, 16 chains/block via i8 MFMA 16x16x64 ----------
// 8 blocks: dir = bid&1, chain group bg = bid>>1 (batches bg*16..+15).
// 512 thr = 8 waves; wave wv owns permuted W rows (128) = units wv*32..+31 x 4 gates.
// Lane l: ch = l&15 (chain/col), qc = l>>4; ac[rt][g] = gate g pre-act of unit
// u = wv*32 + qc*8 + rt, chain ch -> cell update fully lane-local.
// gx: 4 coalesced f16x8 loads from gxp; h: i8 in 8KB double-buffered LDS.
__global__ __launch_bounds__(512,2) void k_rnn(const i32x4* __restrict__ wfrag,
            const f16* __restrict__ gxp, f16* __restrict__ Hc){
  __shared__ alignas(16) unsigned char lhB[2][4][4][16][16]; // [buf][kt][qc][ch][16B] = 8KB
  int bid = blockIdx.x;
  int bg = bid >> 1, dir = bid & 1;
  int tid = threadIdx.x;
  int wv = tid >> 6, lane = tid & 63;
  int qc = lane >> 4, ch = lane & 15;
  int b  = bg*16 + ch;
  int U0 = wv*32 + qc*8;
  const i32x4* wfp = wfrag + (size_t)(dir*8 + wv)*2048 + lane;
  i32x4 a[32];                                   // A-frags (128 VGPRs), a[rt*4+kt]
  #pragma unroll
  for (int i=0;i<32;i++) a[i] = wfp[(size_t)i*64];
  ((unsigned long long*)lhB)[tid] = 0ULL;        // zero buffer 0 (4096 B)
  float c[8];
  #pragma unroll
  for (int r=0;r<8;r++) c[r] = 0.0f;
  const f16* gxb = gxp + (size_t)((bg*2 + dir)*512)*16384 + wv*2048 + qc*512 + ch*32;
  f16* Hcb = Hc + (size_t)b*512*512 + dir*256 + U0;
  const float ISC = 1.0f/(2048.0f*127.0f);
  __syncthreads();
  for (int t=0; t<512; t++){
    int s = dir ? (511-t) : t;
    int cur = t & 1;
    // coalesced gx loads, issued early (consumed after the MFMA burst)
    const f16* gp = gxb + (size_t)s*16384;
    f16x8 g0 = *(const f16x8*)(gp);        // gate i, rt 0..7
    f16x8 g1 = *(const f16x8*)(gp + 8);    // gate f
    f16x8 g2v= *(const f16x8*)(gp + 16);   // gate g
    f16x8 g3 = *(const f16x8*)(gp + 24);   // gate o
    i32x4 hb[4];
    #pragma unroll
    for (int kt=0; kt<4; kt++) hb[kt] = *(const i32x4*)&lhB[cur][kt][qc][ch][0];
    i32x4 ac[8];
    #pragma unroll
    for (int rt=0; rt<8; rt++) ac[rt] = (i32x4){0,0,0,0};
    #pragma unroll
    for (int kt=0; kt<4; kt++){
      #pragma unroll
      for (int rt=0; rt<8; rt++)
        ac[rt] = __builtin_amdgcn_mfma_i32_16x16x64_i8(a[rt*4+kt], hb[kt], ac[rt], 0,0,0);
    }
    f16x8 hv;
    unsigned long long hpack = 0ULL;
    #pragma unroll
    for (int rt=0; rt<8; rt++){
      float p0 = (float)ac[rt][0]*ISC + (float)g0[rt];
      float p1 = (float)ac[rt][1]*ISC + (float)g1[rt];
      float p2 = (float)ac[rt][2]*ISC + (float)g2v[rt];
      float p3 = (float)ac[rt][3]*ISC + (float)g3[rt];
      float ig = sigm(p0), fg = sigm(p1);
      float gg = tanh_(p2), og = sigm(p3);
      c[rt] = fg*c[rt] + ig*gg;
      float h = og*tanh_(c[rt]);
      hv[rt] = (f16)h;
      int q = (int)rintf(h * 127.0f);
      hpack |= ((unsigned long long)(unsigned char)(signed char)q) << (8*rt);
    }
    *(f16x8*)(Hcb + (size_t)s*512) = hv;
    // publish 8 h-bytes at B k-positions u = U0..U0+7:
    // kt' = wv>>1, qc' = (wv&1)*2 + (qc>>1), byte base = (qc&1)*8
    *(unsigned long long*)&lhB[cur^1][wv>>1][(wv&1)*2 + (qc>>1)][ch][(qc&1)*8] = hpack;
    bar_lgkm();
  }
}

// ---------- K3: emissions e[m][k] = Hcat[m] . Wproj[k] + b_proj[k]  (wave per row) ----------
__global__ __launch_bounds__(256) void k_emis(const f16* __restrict__ Hc,
                 const f16* __restrict__ Wp, const float* __restrict__ bp,
                 float* __restrict__ e){
  int w = threadIdx.x >> 6, l = threadIdx.x & 63;
  int m = blockIdx.x*4 + w;
  f16x8 hv = *(const f16x8*)(Hc + (size_t)m*512 + l*8);
  u32x4 hu = __builtin_bit_cast(u32x4, hv);
  #pragma unroll
  for (int k=0;k<9;k++){
    f16x8 wv = *(const f16x8*)(Wp + k*512 + l*8);
    u32x4 wu = __builtin_bit_cast(u32x4, wv);
    float p = 0.f;
    #pragma unroll
    for (int q=0;q<4;q++) p = dot2u(hu[q], wu[q], p);
    #pragma unroll
    for (int off=32; off; off>>=1) p += __shfl_xor(p, off);
    if (l == k) e[(size_t)m*9 + k] = p + bp[k];
  }
}

// ---------- K4: CRF negative-llh pieces per batch (1 wave per batch) ----------
__global__ void k_crf(const float* __restrict__ e, const int* __restrict__ tags,
                      const int* __restrict__ mask, const float* __restrict__ st,
                      const float* __restrict__ en, const float* __restrict__ tr,
                      float* __restrict__ llh){
  int b = blockIdx.x;
  int l = threadIdx.x;
  int j = (l < 9) ? l : 0;
  float Tc[9];
  #pragma unroll
  for (int i=0;i<9;i++) Tc[i] = tr[i*9 + j];
  const float* eb = e + (size_t)b*512*9;
  const int* tb = tags + b*512;
  const int* mb = mask + b*512;
  float a = st[j] + eb[j];
  int t0 = tb[0];
  float num = st[t0] + eb[t0];
  int prev = t0;
  int cnt = (mb[0] != 0) ? 1 : 0;
  for (int s=1; s<512; s++){
    float ej = eb[s*9 + j];
    float vi[9];
    #pragma unroll
    for (int i=0;i<9;i++) vi[i] = __shfl(a, i) + Tc[i];
    float mx = vi[0];
    #pragma unroll
    for (int i=1;i<9;i++) mx = fmaxf(mx, vi[i]);
    float ssum = 0.f;
    #pragma unroll
    for (int i=0;i<9;i++) ssum += expf(vi[i]-mx);
    float anew = ej + mx + logf(ssum);
    int mt = mb[s];
    a = (mt != 0) ? anew : a;
    int tg = tb[s];
    num += (float)mt * (tr[prev*9+tg] + eb[s*9+tg]);
    prev = tg;
    cnt += (mt != 0) ? 1 : 0;
  }
  float av[9];
  #pragma unroll
  for (int i=0;i<9;i++) av[i] = __shfl(a, i) + en[i];
  float mx = av[0];
  #pragma unroll
  for (int i=1;i<9;i++) mx = fmaxf(mx, av[i]);
  float ssum = 0.f;
  #pragma unroll
  for (int i=0;i<9;i++) ssum += expf(av[i]-mx);
  float logZ = mx + logf(ssum);
  if (l == 0){
    int lastt = tb[cnt-1];
    llh[b] = (num + en[lastt]) - logZ;
  }
}

// ---------- K5: final reduce ----------
__global__ void k_red(const float* __restrict__ llh, float* __restrict__ out){
  if (threadIdx.x == 0){
    float s = 0.f;
    for (int i=0;i<64;i++) s += llh[i];
    out[0] = -s / 64.0f;
  }
}

extern "C" void kernel_launch(void* const* d_in, const int* in_sizes, int n_in,
                              void* d_out, int out_size, void* d_ws, size_t ws_size,
                              hipStream_t stream){
  const float* emb  = (const float*)d_in[0];
  const int*   tags = (const int*)d_in[1];
  const int*   mask = (const int*)d_in[2];
  const float* wihf = (const float*)d_in[3];
  const float* whhf = (const float*)d_in[4];
  const float* bfp  = (const float*)d_in[5];
  const float* wihb = (const float*)d_in[6];
  const float* whhb = (const float*)d_in[7];
  const float* bbp  = (const float*)d_in[8];
  const float* wprj = (const float*)d_in[9];
  const float* bprj = (const float*)d_in[10];
  const float* st   = (const float*)d_in[11];
  const float* en   = (const float*)d_in[12];
  const float* tr   = (const float*)d_in[13];

  char* ws = (char*)d_ws;
  f16*   Xf    = (f16*)(ws + 0);                 // 50,331,648 B (aliased by Hc later)
  f16*   Wcat  = (f16*)(ws + 50331648);          //  3,145,728 B
  u32x4* Wpack = (u32x4*)(ws + 53477376);        //    524,288 B used
  f16*   Wpj   = (f16*)(ws + 54525952);          //      9,216 B
  f16*   gxp   = (f16*)(ws + 54535168);          // 134,217,728 B (shuffled layout)
  float* e     = (float*)(ws + 188752896);       //  1,179,648 B
  float* llh   = (float*)(ws + 189932544);       //        256 B
  f16*   Hc    = Xf;   // safe alias: X only read by k_gemm, which precedes k_rnn

  hipLaunchKernelGGL(k_cvt,    dim3(12288), dim3(256), 0, stream, emb,  Xf, 25165824);
  hipLaunchKernelGGL(k_cvt,    dim3(384),   dim3(256), 0, stream, wihf, Wcat,          786432);
  hipLaunchKernelGGL(k_cvt,    dim3(384),   dim3(256), 0, stream, wihb, Wcat + 786432, 786432);
  hipLaunchKernelGGL(k_cvt,    dim3(3),     dim3(256), 0, stream, wprj, Wpj, 4608);
  hipLaunchKernelGGL(k_wpack7, dim3(128),   dim3(256), 0, stream, whhf, whhb, Wpack);
  hipLaunchKernelGGL(k_gemm,   dim3(4096),  dim3(256), 0, stream, Xf, Wcat, bfp, bbp, gxp);
  hipLaunchKernelGGL(k_rnn,    dim3(8),     dim3(512), 0, stream, (const i32x4*)Wpack, gxp, Hc);
  hipLaunchKernelGGL(k_emis,   dim3(8192),  dim3(256), 0, stream, Hc, Wpj, bprj, e);
  hipLaunchKernelGGL(k_crf,    dim3(64),    dim3(64),  0, stream, e, tags, mask, st, en, tr, llh);
  hipLaunchKernelGGL(k_red,    dim3(1),     dim3(64),  0, stream, llh, (float*)d_out);
}

// Round 9
// 1013.068 us; speedup vs baseline: 2.4074x; 2.3258x over previous
//
#include <hip/hip_runtime.h>

typedef _Float16 f16;
typedef _Float16 f16x2 __attribute__((ext_vector_type(2)));
typedef _Float16 f16x4 __attribute__((ext_vector_type(4)));
typedef _Float16 f16x8 __attribute__((ext_vector_type(8)));
typedef float    f32x4 __attribute__((ext_vector_type(4)));
typedef int      i32x4 __attribute__((ext_vector_type(4)));
typedef unsigned int u32x4 __attribute__((ext_vector_type(4)));

// ---------- helpers ----------
__device__ __forceinline__ float dot2u(unsigned a, unsigned b, float c){
  return __builtin_amdgcn_fdot2(__builtin_bit_cast(f16x2, a),
                                __builtin_bit_cast(f16x2, b), c, false);
}
__device__ __forceinline__ float sigm(float x){ return 1.0f/(1.0f+__expf(-x)); }
__device__ __forceinline__ float tanh_(float x){
  x = fminf(fmaxf(x, -20.f), 20.f);
  return 1.0f - 2.0f/(__expf(2.0f*x)+1.0f);
}

// Barrier that does NOT drain vmcnt (in-loop cross-thread traffic is LDS-only;
// global prefetches/stores stay in flight across steps).
__device__ __forceinline__ void bar_lgkm(){
  asm volatile("s_waitcnt lgkmcnt(0)\n\ts_barrier" ::: "memory");
}

// ---------- K0: fp32 -> f16 convert (8 elems/thread) ----------
__global__ void k_cvt(const float* __restrict__ src, f16* __restrict__ dst, int n){
  int i = (blockIdx.x*256 + threadIdx.x)*8;
  if (i >= n) return;
  float4 a = *(const float4*)(src + i);
  float4 b = *(const float4*)(src + i + 4);
  f16x8 o;
  o[0]=(f16)a.x; o[1]=(f16)a.y; o[2]=(f16)a.z; o[3]=(f16)a.w;
  o[4]=(f16)b.x; o[5]=(f16)b.y; o[6]=(f16)b.z; o[7]=(f16)b.w;
  *(f16x8*)(dst+i) = o;
}

// ---------- K0c: pack W_hh into i8 MFMA A-frags (16x16x64), gate-interleaved perm ----
// Entry idx = dir*16384 + wv*2048 + rt*256 + kt*64 + lane  (16 bytes each).
// A-frag: lane holds A[row = lane&15][k = kt*64 + (lane>>4)*16 + j].
// Row perm: row i of tile (wv,rt): unit u = wv*32 + (i>>2)*8 + rt, gate = i&3
//   -> W_hh source row = gate*256 + u.  Weights scaled x2048, clamped [-127,127].
__global__ void k_wpack7(const float* __restrict__ whf, const float* __restrict__ whb,
                         u32x4* __restrict__ wf){
  int idx = blockIdx.x*256 + threadIdx.x;    // 0..32767
  int lane = idx & 63;
  int kt   = (idx >> 6) & 3;
  int rt   = (idx >> 8) & 7;
  int wv   = (idx >> 11) & 7;
  int dir  = (idx >> 14) & 1;
  const float* w = dir ? whb : whf;
  int i  = lane & 15;
  int u  = wv*32 + (i >> 2)*8 + rt;
  int g  = i & 3;
  int k0 = kt*64 + (lane >> 4)*16;
  const float* row = w + (size_t)(g*256 + u)*256 + k0;
  u32x4 v = {0,0,0,0};
  #pragma unroll
  for (int j=0;j<16;j++){
    int q = (int)rintf(row[j] * 2048.0f);
    q = q > 127 ? 127 : (q < -127 ? -127 : q);
    v[j>>2] |= ((unsigned)(unsigned char)(signed char)q) << ((j&3)*8);
  }
  wf[idx] = v;
}

// ---------- K1: gxq = X @ Wcat^T + bias, layout [chain=b*2+dir][s][u*4+g] f16 ----------
__global__ __launch_bounds__(256) void k_gemm(const f16* __restrict__ A,
                                              const f16* __restrict__ Bw,
                                              const float* __restrict__ bf_,
                                              const float* __restrict__ bb_,
                                              f16* __restrict__ C){
  __shared__ alignas(16) f16 As[128][64];
  __shared__ alignas(16) f16 Bs[128][64];
  int bid = blockIdx.x;
  int bm = bid >> 4, bn = bid & 15;
  int tid = threadIdx.x;
  int w = tid >> 6, l = tid & 63;
  int wm = w >> 1, wn = w & 1;
  f32x4 acc[4][4] = {};
  int srow = tid >> 3;
  int scol = (tid & 7)*8;
  const f16* Ag = A  + (size_t)(bm*128)*768 + scol;
  const f16* Bg = Bw + (size_t)(bn*128)*768 + scol;
  int fr = l & 15, kg = l >> 4;
  for (int k0 = 0; k0 < 768; k0 += 64){
    #pragma unroll
    for (int q=0;q<4;q++){
      int rr = srow + 32*q;
      u32x4 av = *(const u32x4*)(Ag + rr*768 + k0);
      u32x4 bv = *(const u32x4*)(Bg + rr*768 + k0);
      *(u32x4*)&As[rr][scol] = av;
      *(u32x4*)&Bs[rr][scol] = bv;
    }
    __syncthreads();
    #pragma unroll
    for (int ks=0; ks<2; ks++){
      f16x8 af[4], bf[4];
      #pragma unroll
      for (int mi=0;mi<4;mi++) af[mi] = *(const f16x8*)&As[wm*64+mi*16+fr][ks*32+kg*8];
      #pragma unroll
      for (int ni=0;ni<4;ni++) bf[ni] = *(const f16x8*)&Bs[wn*64+ni*16+fr][ks*32+kg*8];
      #pragma unroll
      for (int mi=0;mi<4;mi++)
        #pragma unroll
        for (int ni=0;ni<4;ni++)
          acc[mi][ni] = __builtin_amdgcn_mfma_f32_16x16x32_f16(af[mi], bf[ni], acc[mi][ni], 0,0,0);
    }
    __syncthreads();
  }
  int fq = l >> 4;
  #pragma unroll
  for (int ni=0;ni<4;ni++){
    int nc = bn*128 + wn*64 + ni*16 + fr;
    int dirc = nc >> 10, tt = nc & 1023;
    int g = tt >> 8, u = tt & 255;
    float bv = (nc < 1024) ? bf_[nc] : bb_[nc - 1024];
    #pragma unroll
    for (int mi=0;mi<4;mi++){
      int mrow = bm*128 + wm*64 + mi*16 + fq*4;
      #pragma unroll
      for (int r=0;r<4;r++){
        int m = mrow + r;
        int b2 = m >> 9, s = m & 511;
        size_t q = ((size_t)(b2*2 + dirc)*512 + s)*1024 + (size_t)u*4 + g;
        C[q] = (f16)(acc[mi][ni][r] + bv);
      }
    }
  }
}

// ---------- K2: recurrence. 128 blocks (1 chain each), i8 MFMA 16x16x64 ----------
// 512 thr = 8 waves; wave wv owns permuted W rows = units wv*32..+31 x 4 gates.
// B = h(i8) replicated to all 16 cols (broadcast ds_read_b128 from 256B buffer).
// C layout + row perm puts all 4 gates of unit wv*32+qc*8+rt in one lane's
// acc[rt] quad -> cell update lane-local after a static cndmask extract of rt=ch&7.
// Designated lanes ch<8 store h (f16 global, i8 LDS byte). One lgkm barrier/step.
__global__ __launch_bounds__(512,2) void k_rnn(const i32x4* __restrict__ wfrag,
            const f16* __restrict__ gxq, f16* __restrict__ Hc){
  __shared__ alignas(16) unsigned char lhB[2][256];
  __shared__ char lds_pad[86016];      // force 1 block/CU (no co-resident straggler)
  int bid = blockIdx.x;                // 0..127
  int b = bid >> 1, dir = bid & 1;
  int tid = threadIdx.x;
  int wv = tid >> 6, lane = tid & 63;
  int qc = lane >> 4, ch = lane & 15;
  int r_ = ch & 7;
  int u  = wv*32 + qc*8 + r_;
  bool act = (ch < 8);
  const i32x4* wfp = wfrag + (size_t)(dir*8 + wv)*2048 + lane;
  i32x4 a[32];                         // A-frags a[rt*4+kt] (128 regs)
  #pragma unroll
  for (int i=0;i<32;i++) a[i] = wfp[(size_t)i*64];
  if (tid < 64) ((unsigned long long*)lhB)[tid] = 0ULL;   // zero both buffers
  lds_pad[tid] = 0;                    // keep pad allocation live
  float c = 0.0f;
  const f16* gxc = gxq + (size_t)((b*2 + dir)*512)*1024 + (size_t)u*4;
  f16* Hcb = Hc + (size_t)b*512*512 + dir*256 + u;
  const float ISC = 1.0f/(2048.0f*127.0f);
  __syncthreads();
  int s0 = dir ? 511 : 0;
  f16x4 gn = *(const f16x4*)(gxc + (size_t)s0*1024);      // prefetch step 0
  for (int t=0; t<512; t++){
    int s = dir ? (511-t) : t;
    int cur = t & 1;
    // prefetch next step's gx (one 8B coalesced load; waited at use next iter)
    int tn = (t < 511) ? t+1 : 511;
    int sn = dir ? (511 - tn) : tn;
    f16x4 gf = *(const f16x4*)(gxc + (size_t)sn*1024);
    // B-frags: broadcast reads of the 256B h buffer
    i32x4 hb[4];
    #pragma unroll
    for (int kt=0; kt<4; kt++) hb[kt] = *(const i32x4*)&lhB[cur][kt*64 + qc*16];
    i32x4 ac[8];
    #pragma unroll
    for (int rt=0; rt<8; rt++) ac[rt] = (i32x4){0,0,0,0};
    #pragma unroll
    for (int kt=0; kt<4; kt++){
      #pragma unroll
      for (int rt=0; rt<8; rt++)
        ac[rt] = __builtin_amdgcn_mfma_i32_16x16x64_i8(a[rt*4+kt], hb[kt], ac[rt], 0,0,0);
    }
    // static-index extract of this lane's rt = r_ (rule-20-safe)
    i32x4 pv = ac[0];
    #pragma unroll
    for (int rt=1; rt<8; rt++){
      pv[0] = (r_ == rt) ? ac[rt][0] : pv[0];
      pv[1] = (r_ == rt) ? ac[rt][1] : pv[1];
      pv[2] = (r_ == rt) ? ac[rt][2] : pv[2];
      pv[3] = (r_ == rt) ? ac[rt][3] : pv[3];
    }
    float p0 = (float)pv[0]*ISC + (float)gn[0];
    float p1 = (float)pv[1]*ISC + (float)gn[1];
    float p2 = (float)pv[2]*ISC + (float)gn[2];
    float p3 = (float)pv[3]*ISC + (float)gn[3];
    float ig = sigm(p0), fg = sigm(p1);
    float gg = tanh_(p2), og = sigm(p3);
    c = fg*c + ig*gg;
    float h = og*tanh_(c);
    if (act){
      Hcb[(size_t)s*512] = (f16)h;
      int q = (int)rintf(h * 127.0f);
      lhB[cur^1][u] = (unsigned char)(signed char)q;
    }
    gn = gf;
    bar_lgkm();
  }
}

// ---------- K3: emissions e[m][k] = Hcat[m] . Wproj[k] + b_proj[k]  (wave per row) ----------
__global__ __launch_bounds__(256) void k_emis(const f16* __restrict__ Hc,
                 const f16* __restrict__ Wp, const float* __restrict__ bp,
                 float* __restrict__ e){
  int w = threadIdx.x >> 6, l = threadIdx.x & 63;
  int m = blockIdx.x*4 + w;
  f16x8 hv = *(const f16x8*)(Hc + (size_t)m*512 + l*8);
  u32x4 hu = __builtin_bit_cast(u32x4, hv);
  #pragma unroll
  for (int k=0;k<9;k++){
    f16x8 wv = *(const f16x8*)(Wp + k*512 + l*8);
    u32x4 wu = __builtin_bit_cast(u32x4, wv);
    float p = 0.f;
    #pragma unroll
    for (int q=0;q<4;q++) p = dot2u(hu[q], wu[q], p);
    #pragma unroll
    for (int off=32; off; off>>=1) p += __shfl_xor(p, off);
    if (l == k) e[(size_t)m*9 + k] = p + bp[k];
  }
}

// ---------- K4: CRF negative-llh pieces per batch (1 wave per batch) ----------
__global__ void k_crf(const float* __restrict__ e, const int* __restrict__ tags,
                      const int* __restrict__ mask, const float* __restrict__ st,
                      const float* __restrict__ en, const float* __restrict__ tr,
                      float* __restrict__ llh){
  int b = blockIdx.x;
  int l = threadIdx.x;
  int j = (l < 9) ? l : 0;
  float Tc[9];
  #pragma unroll
  for (int i=0;i<9;i++) Tc[i] = tr[i*9 + j];
  const float* eb = e + (size_t)b*512*9;
  const int* tb = tags + b*512;
  const int* mb = mask + b*512;
  float a = st[j] + eb[j];
  int t0 = tb[0];
  float num = st[t0] + eb[t0];
  int prev = t0;
  int cnt = (mb[0] != 0) ? 1 : 0;
  for (int s=1; s<512; s++){
    float ej = eb[s*9 + j];
    float vi[9];
    #pragma unroll
    for (int i=0;i<9;i++) vi[i] = __shfl(a, i) + Tc[i];
    float mx = vi[0];
    #pragma unroll
    for (int i=1;i<9;i++) mx = fmaxf(mx, vi[i]);
    float ssum = 0.f;
    #pragma unroll
    for (int i=0;i<9;i++) ssum += expf(vi[i]-mx);
    float anew = ej + mx + logf(ssum);
    int mt = mb[s];
    a = (mt != 0) ? anew : a;
    int tg = tb[s];
    num += (float)mt * (tr[prev*9+tg] + eb[s*9+tg]);
    prev = tg;
    cnt += (mt != 0) ? 1 : 0;
  }
  float av[9];
  #pragma unroll
  for (int i=0;i<9;i++) av[i] = __shfl(a, i) + en[i];
  float mx = av[0];
  #pragma unroll
  for (int i=1;i<9;i++) mx = fmaxf(mx, av[i]);
  float ssum = 0.f;
  #pragma unroll
  for (int i=0;i<9;i++) ssum += expf(av[i]-mx);
  float logZ = mx + logf(ssum);
  if (l == 0){
    int lastt = tb[cnt-1];
    llh[b] = (num + en[lastt]) - logZ;
  }
}

// ---------- K5: final reduce ----------
__global__ void k_red(const float* __restrict__ llh, float* __restrict__ out){
  if (threadIdx.x == 0){
    float s = 0.f;
    for (int i=0;i<64;i++) s += llh[i];
    out[0] = -s / 64.0f;
  }
}

extern "C" void kernel_launch(void* const* d_in, const int* in_sizes, int n_in,
                              void* d_out, int out_size, void* d_ws, size_t ws_size,
                              hipStream_t stream){
  const float* emb  = (const float*)d_in[0];
  const int*   tags = (const int*)d_in[1];
  const int*   mask = (const int*)d_in[2];
  const float* wihf = (const float*)d_in[3];
  const float* whhf = (const float*)d_in[4];
  const float* bfp  = (const float*)d_in[5];
  const float* wihb = (const float*)d_in[6];
  const float* whhb = (const float*)d_in[7];
  const float* bbp  = (const float*)d_in[8];
  const float* wprj = (const float*)d_in[9];
  const float* bprj = (const float*)d_in[10];
  const float* st   = (const float*)d_in[11];
  const float* en   = (const float*)d_in[12];
  const float* tr   = (const float*)d_in[13];

  char* ws = (char*)d_ws;
  f16*   Xf    = (f16*)(ws + 0);                 // 50,331,648 B (aliased by Hc later)
  f16*   Wcat  = (f16*)(ws + 50331648);          //  3,145,728 B
  u32x4* Wpack = (u32x4*)(ws + 53477376);        //    524,288 B used
  f16*   Wpj   = (f16*)(ws + 54525952);          //      9,216 B
  f16*   gxq   = (f16*)(ws + 54535168);          // 134,217,728 B ([chain][s][u*4+g])
  float* e     = (float*)(ws + 188752896);       //  1,179,648 B
  float* llh   = (float*)(ws + 189932544);       //        256 B
  f16*   Hc    = Xf;   // safe alias: X only read by k_gemm, which precedes k_rnn

  hipLaunchKernelGGL(k_cvt,    dim3(12288), dim3(256), 0, stream, emb,  Xf, 25165824);
  hipLaunchKernelGGL(k_cvt,    dim3(384),   dim3(256), 0, stream, wihf, Wcat,          786432);
  hipLaunchKernelGGL(k_cvt,    dim3(384),   dim3(256), 0, stream, wihb, Wcat + 786432, 786432);
  hipLaunchKernelGGL(k_cvt,    dim3(3),     dim3(256), 0, stream, wprj, Wpj, 4608);
  hipLaunchKernelGGL(k_wpack7, dim3(128),   dim3(256), 0, stream, whhf, whhb, Wpack);
  hipLaunchKernelGGL(k_gemm,   dim3(4096),  dim3(256), 0, stream, Xf, Wcat, bfp, bbp, gxq);
  hipLaunchKernelGGL(k_rnn,    dim3(128),   dim3(512), 0, stream, (const i32x4*)Wpack, gxq, Hc);
  hipLaunchKernelGGL(k_emis,   dim3(8192),  dim3(256), 0, stream, Hc, Wpj, bprj, e);
  hipLaunchKernelGGL(k_crf,    dim3(64),    dim3(64),  0, stream, e, tags, mask, st, en, tr, llh);
  hipLaunchKernelGGL(k_red,    dim3(1),     dim3(64),  0, stream, llh, (float*)d_out);
}

// Round 10
// 934.573 us; speedup vs baseline: 2.6096x; 1.0840x over previous
//
#include <hip/hip_runtime.h>

typedef _Float16 f16;
typedef _Float16 f16x2 __attribute__((ext_vector_type(2)));
typedef _Float16 f16x4 __attribute__((ext_vector_type(4)));
typedef _Float16 f16x8 __attribute__((ext_vector_type(8)));
typedef float    f32x4 __attribute__((ext_vector_type(4)));
typedef int      i32x4 __attribute__((ext_vector_type(4)));
typedef unsigned int u32x4 __attribute__((ext_vector_type(4)));

// ---------- helpers ----------
__device__ __forceinline__ float dot2u(unsigned a, unsigned b, float c){
  return __builtin_amdgcn_fdot2(__builtin_bit_cast(f16x2, a),
                                __builtin_bit_cast(f16x2, b), c, false);
}
__device__ __forceinline__ float sigm(float x){ return 1.0f/(1.0f+__expf(-x)); }
__device__ __forceinline__ float tanh_(float x){
  x = fminf(fmaxf(x, -20.f), 20.f);
  return 1.0f - 2.0f/(__expf(2.0f*x)+1.0f);
}

// Barrier that does NOT drain vmcnt (in-loop cross-thread traffic is LDS-only;
// global prefetches/stores stay in flight across steps).
__device__ __forceinline__ void bar_lgkm(){
  asm volatile("s_waitcnt lgkmcnt(0)\n\ts_barrier" ::: "memory");
}

#if __has_builtin(__builtin_amdgcn_global_load_lds)
#define HAVE_GLL 1
#else
#define HAVE_GLL 0
#endif

// ---------- K0: fp32 -> f16 convert (8 elems/thread) ----------
__global__ void k_cvt(const float* __restrict__ src, f16* __restrict__ dst, int n){
  int i = (blockIdx.x*256 + threadIdx.x)*8;
  if (i >= n) return;
  float4 a = *(const float4*)(src + i);
  float4 b = *(const float4*)(src + i + 4);
  f16x8 o;
  o[0]=(f16)a.x; o[1]=(f16)a.y; o[2]=(f16)a.z; o[3]=(f16)a.w;
  o[4]=(f16)b.x; o[5]=(f16)b.y; o[6]=(f16)b.z; o[7]=(f16)b.w;
  *(f16x8*)(dst+i) = o;
}

// ---------- K0c: pack W_hh into i8 MFMA A-frags (16x16x64), gate-interleaved perm ----
// Entry idx = dir*16384 + wv*2048 + rt*256 + kt*64 + lane  (16 bytes each).
// A-frag: lane holds A[row = lane&15][k = kt*64 + (lane>>4)*16 + j].
// Row perm: row i of tile (wv,rt): unit u = wv*32 + (i>>2)*8 + rt, gate = i&3
//   -> W_hh source row = gate*256 + u.  Weights scaled x2048, clamped [-127,127].
__global__ void k_wpack7(const float* __restrict__ whf, const float* __restrict__ whb,
                         u32x4* __restrict__ wf){
  int idx = blockIdx.x*256 + threadIdx.x;    // 0..32767
  int lane = idx & 63;
  int kt   = (idx >> 6) & 3;
  int rt   = (idx >> 8) & 7;
  int wv   = (idx >> 11) & 7;
  int dir  = (idx >> 14) & 1;
  const float* w = dir ? whb : whf;
  int i  = lane & 15;
  int u  = wv*32 + (i >> 2)*8 + rt;
  int g  = i & 3;
  int k0 = kt*64 + (lane >> 4)*16;
  const float* row = w + (size_t)(g*256 + u)*256 + k0;
  u32x4 v = {0,0,0,0};
  #pragma unroll
  for (int j=0;j<16;j++){
    int q = (int)rintf(row[j] * 2048.0f);
    q = q > 127 ? 127 : (q < -127 ? -127 : q);
    v[j>>2] |= ((unsigned)(unsigned char)(signed char)q) << ((j&3)*8);
  }
  wf[idx] = v;
}

// ---------- K1: gx = X(32768x768) @ Wcat(2048x768)^T + bias, plain [m][n] f16 ----------
// Staging via global_load_lds width 16 (wave-uniform LDS base + lane*16).
__global__ __launch_bounds__(256) void k_gemm(const f16* __restrict__ A,
                                              const f16* __restrict__ Bw,
                                              const float* __restrict__ bf_,
                                              const float* __restrict__ bb_,
                                              f16* __restrict__ C){
  __shared__ alignas(16) f16 As[128][64];
  __shared__ alignas(16) f16 Bs[128][64];
  int bid = blockIdx.x;
  int bm = bid >> 4, bn = bid & 15;
  int tid = threadIdx.x;
  int w = tid >> 6, l = tid & 63;
  int wm = w >> 1, wn = w & 1;
  f32x4 acc[4][4] = {};
  const f16* Agb = A  + (size_t)(bm*128)*768;
  const f16* Bgb = Bw + (size_t)(bn*128)*768;
  int fr = l & 15, kg = l >> 4;
#if !HAVE_GLL
  int srow = tid >> 3;
  int scol = (tid & 7)*8;
#endif
  for (int k0 = 0; k0 < 768; k0 += 64){
#if HAVE_GLL
    // wave w stages rows [w*32, w*32+32) of As and Bs: 4 insts each, 8 rows/inst
    #pragma unroll
    for (int i=0;i<4;i++){
      int row = (w*4+i)*8 + (l>>3);
      int col = (l&7)*8;
      __builtin_amdgcn_global_load_lds(
        (const __attribute__((address_space(1))) void*)(Agb + (size_t)row*768 + k0 + col),
        (__attribute__((address_space(3))) void*)((char*)&As[0][0] + (w*4+i)*1024),
        16, 0, 0);
      __builtin_amdgcn_global_load_lds(
        (const __attribute__((address_space(1))) void*)(Bgb + (size_t)row*768 + k0 + col),
        (__attribute__((address_space(3))) void*)((char*)&Bs[0][0] + (w*4+i)*1024),
        16, 0, 0);
    }
#else
    #pragma unroll
    for (int q=0;q<4;q++){
      int rr = srow + 32*q;
      u32x4 av = *(const u32x4*)(Agb + (size_t)rr*768 + k0 + scol);
      u32x4 bv = *(const u32x4*)(Bgb + (size_t)rr*768 + k0 + scol);
      *(u32x4*)&As[rr][scol] = av;
      *(u32x4*)&Bs[rr][scol] = bv;
    }
#endif
    __syncthreads();
    #pragma unroll
    for (int ks=0; ks<2; ks++){
      f16x8 af[4], bf[4];
      #pragma unroll
      for (int mi=0;mi<4;mi++) af[mi] = *(const f16x8*)&As[wm*64+mi*16+fr][ks*32+kg*8];
      #pragma unroll
      for (int ni=0;ni<4;ni++) bf[ni] = *(const f16x8*)&Bs[wn*64+ni*16+fr][ks*32+kg*8];
      #pragma unroll
      for (int mi=0;mi<4;mi++)
        #pragma unroll
        for (int ni=0;ni<4;ni++)
          acc[mi][ni] = __builtin_amdgcn_mfma_f32_16x16x32_f16(af[mi], bf[ni], acc[mi][ni], 0,0,0);
    }
    __syncthreads();
  }
  int fq = l >> 4;
  #pragma unroll
  for (int ni=0;ni<4;ni++){
    int ncol = bn*128 + wn*64 + ni*16 + fr;
    float bv = (ncol < 1024) ? bf_[ncol] : bb_[ncol - 1024];
    #pragma unroll
    for (int mi=0;mi<4;mi++){
      int mrow = bm*128 + wm*64 + mi*16 + fq*4;
      #pragma unroll
      for (int r=0;r<4;r++)
        C[(size_t)(mrow+r)*2048 + ncol] = (f16)(acc[mi][ni][r] + bv);
    }
  }
}

// ---------- K2: recurrence. 128 blocks (1 chain each), i8 MFMA 16x16x64 ----------
// 512 thr = 8 waves; wave wv owns permuted W rows = units wv*32..+31 x 4 gates.
// B = h(i8) replicated to all 16 cols (broadcast ds_read_b128 from 256B buffer).
// C layout + row perm puts all 4 gates of unit wv*32+qc*8+rt in one lane's
// acc[rt] quad -> cell update lane-local after static cndmask extract of rt=ch&7.
// gx read from PLAIN layout: 4 scalar f16 loads (64B segments/wave/gate),
// prefetched one step ahead. One lgkm barrier per step.
__global__ __launch_bounds__(512,2) void k_rnn(const i32x4* __restrict__ wfrag,
            const f16* __restrict__ gx, f16* __restrict__ Hc){
  __shared__ alignas(16) unsigned char lhB[2][256];
  int bid = blockIdx.x;                // 0..127
  int b = bid >> 1, dir = bid & 1;
  int tid = threadIdx.x;
  int wv = tid >> 6, lane = tid & 63;
  int qc = lane >> 4, ch = lane & 15;
  int r_ = ch & 7;
  int u  = wv*32 + qc*8 + r_;
  bool act = (ch < 8);
  const i32x4* wfp = wfrag + (size_t)(dir*8 + wv)*2048 + lane;
  i32x4 a[32];                         // A-frags a[rt*4+kt] (128 regs)
  #pragma unroll
  for (int i=0;i<32;i++) a[i] = wfp[(size_t)i*64];
  if (tid < 64) ((unsigned long long*)lhB)[tid] = 0ULL;   // zero both buffers
  float c = 0.0f;
  const f16* gxc = gx + (size_t)(b*512)*2048 + dir*1024 + u;
  f16* Hcb = Hc + (size_t)b*512*512 + dir*256 + u;
  const float ISC = 1.0f/(2048.0f*127.0f);
  __syncthreads();
  int s0 = dir ? 511 : 0;
  const f16* gp0 = gxc + (size_t)s0*2048;
  f16 gn0 = gp0[0], gn1 = gp0[256], gn2 = gp0[512], gn3 = gp0[768];
  for (int t=0; t<512; t++){
    int s = dir ? (511-t) : t;
    int cur = t & 1;
    // prefetch next step's gx (4 coalesced scalar loads; used next iteration)
    int tn = (t < 511) ? t+1 : 511;
    int sn = dir ? (511 - tn) : tn;
    const f16* gp = gxc + (size_t)sn*2048;
    f16 f0 = gp[0], f1 = gp[256], f2 = gp[512], f3 = gp[768];
    // B-frags: broadcast reads of the 256B h buffer
    i32x4 hb[4];
    #pragma unroll
    for (int kt=0; kt<4; kt++) hb[kt] = *(const i32x4*)&lhB[cur][kt*64 + qc*16];
    i32x4 ac[8];
    #pragma unroll
    for (int rt=0; rt<8; rt++) ac[rt] = (i32x4){0,0,0,0};
    #pragma unroll
    for (int kt=0; kt<4; kt++){
      #pragma unroll
      for (int rt=0; rt<8; rt++)
        ac[rt] = __builtin_amdgcn_mfma_i32_16x16x64_i8(a[rt*4+kt], hb[kt], ac[rt], 0,0,0);
    }
    // static-index extract of this lane's rt = r_ (rule-20-safe)
    i32x4 pv = ac[0];
    #pragma unroll
    for (int rt=1; rt<8; rt++){
      pv[0] = (r_ == rt) ? ac[rt][0] : pv[0];
      pv[1] = (r_ == rt) ? ac[rt][1] : pv[1];
      pv[2] = (r_ == rt) ? ac[rt][2] : pv[2];
      pv[3] = (r_ == rt) ? ac[rt][3] : pv[3];
    }
    float p0 = (float)pv[0]*ISC + (float)gn0;
    float p1 = (float)pv[1]*ISC + (float)gn1;
    float p2 = (float)pv[2]*ISC + (float)gn2;
    float p3 = (float)pv[3]*ISC + (float)gn3;
    float ig = sigm(p0), fg = sigm(p1);
    float gg = tanh_(p2), og = sigm(p3);
    c = fg*c + ig*gg;
    float h = og*tanh_(c);
    if (act){
      Hcb[(size_t)s*512] = (f16)h;
      int q = (int)rintf(h * 127.0f);
      lhB[cur^1][u] = (unsigned char)(signed char)q;
    }
    gn0 = f0; gn1 = f1; gn2 = f2; gn3 = f3;
    bar_lgkm();
  }
}

// ---------- K3: emissions e[m][k] = Hcat[m] . Wproj[k] + b_proj[k]  (wave per row) ----------
__global__ __launch_bounds__(256) void k_emis(const f16* __restrict__ Hc,
                 const f16* __restrict__ Wp, const float* __restrict__ bp,
                 float* __restrict__ e){
  int w = threadIdx.x >> 6, l = threadIdx.x & 63;
  int m = blockIdx.x*4 + w;
  f16x8 hv = *(const f16x8*)(Hc + (size_t)m*512 + l*8);
  u32x4 hu = __builtin_bit_cast(u32x4, hv);
  #pragma unroll
  for (int k=0;k<9;k++){
    f16x8 wv = *(const f16x8*)(Wp + k*512 + l*8);
    u32x4 wu = __builtin_bit_cast(u32x4, wv);
    float p = 0.f;
    #pragma unroll
    for (int q=0;q<4;q++) p = dot2u(hu[q], wu[q], p);
    #pragma unroll
    for (int off=32; off; off>>=1) p += __shfl_xor(p, off);
    if (l == k) e[(size_t)m*9 + k] = p + bp[k];
  }
}

// ---------- K4: CRF negative-llh pieces per batch (1 wave per batch) ----------
// alpha broadcast via v_readlane (SALU) instead of 9 ds_bpermute per step.
__global__ void k_crf(const float* __restrict__ e, const int* __restrict__ tags,
                      const int* __restrict__ mask, const float* __restrict__ st,
                      const float* __restrict__ en, const float* __restrict__ tr,
                      float* __restrict__ llh){
  int b = blockIdx.x;
  int l = threadIdx.x;
  int j = (l < 9) ? l : 0;
  float Tc[9];
  #pragma unroll
  for (int i=0;i<9;i++) Tc[i] = tr[i*9 + j];
  const float* eb = e + (size_t)b*512*9;
  const int* tb = tags + b*512;
  const int* mb = mask + b*512;
  float a = st[j] + eb[j];
  int t0 = tb[0];
  float num = st[t0] + eb[t0];
  int prev = t0;
  int cnt = (mb[0] != 0) ? 1 : 0;
  for (int s=1; s<512; s++){
    float ej = eb[s*9 + j];
    float vi[9];
    #pragma unroll
    for (int i=0;i<9;i++){
      float ai = __builtin_bit_cast(float,
                   __builtin_amdgcn_readlane(__builtin_bit_cast(int, a), i));
      vi[i] = ai + Tc[i];
    }
    float mx = vi[0];
    #pragma unroll
    for (int i=1;i<9;i++) mx = fmaxf(mx, vi[i]);
    float ssum = 0.f;
    #pragma unroll
    for (int i=0;i<9;i++) ssum += expf(vi[i]-mx);
    float anew = ej + mx + logf(ssum);
    int mt = mb[s];
    a = (mt != 0) ? anew : a;
    int tg = tb[s];
    num += (float)mt * (tr[prev*9+tg] + eb[s*9+tg]);
    prev = tg;
    cnt += (mt != 0) ? 1 : 0;
  }
  float av[9];
  #pragma unroll
  for (int i=0;i<9;i++){
    float ai = __builtin_bit_cast(float,
                 __builtin_amdgcn_readlane(__builtin_bit_cast(int, a), i));
    av[i] = ai + en[i];
  }
  float mx = av[0];
  #pragma unroll
  for (int i=1;i<9;i++) mx = fmaxf(mx, av[i]);
  float ssum = 0.f;
  #pragma unroll
  for (int i=0;i<9;i++) ssum += expf(av[i]-mx);
  float logZ = mx + logf(ssum);
  if (l == 0){
    int lastt = tb[cnt-1];
    llh[b] = (num + en[lastt]) - logZ;
  }
}

// ---------- K5: final reduce ----------
__global__ void k_red(const float* __restrict__ llh, float* __restrict__ out){
  if (threadIdx.x == 0){
    float s = 0.f;
    for (int i=0;i<64;i++) s += llh[i];
    out[0] = -s / 64.0f;
  }
}

extern "C" void kernel_launch(void* const* d_in, const int* in_sizes, int n_in,
                              void* d_out, int out_size, void* d_ws, size_t ws_size,
                              hipStream_t stream){
  const float* emb  = (const float*)d_in[0];
  const int*   tags = (const int*)d_in[1];
  const int*   mask = (const int*)d_in[2];
  const float* wihf = (const float*)d_in[3];
  const float* whhf = (const float*)d_in[4];
  const float* bfp  = (const float*)d_in[5];
  const float* wihb = (const float*)d_in[6];
  const float* whhb = (const float*)d_in[7];
  const float* bbp  = (const float*)d_in[8];
  const float* wprj = (const float*)d_in[9];
  const float* bprj = (const float*)d_in[10];
  const float* st   = (const float*)d_in[11];
  const float* en   = (const float*)d_in[12];
  const float* tr   = (const float*)d_in[13];

  char* ws = (char*)d_ws;
  f16*   Xf    = (f16*)(ws + 0);                 // 50,331,648 B (aliased by Hc later)
  f16*   Wcat  = (f16*)(ws + 50331648);          //  3,145,728 B
  u32x4* Wpack = (u32x4*)(ws + 53477376);        //    524,288 B used
  f16*   Wpj   = (f16*)(ws + 54525952);          //      9,216 B
  f16*   gx    = (f16*)(ws + 54535168);          // 134,217,728 B (plain [m][n])
  float* e     = (float*)(ws + 188752896);       //  1,179,648 B
  float* llh   = (float*)(ws + 189932544);       //        256 B
  f16*   Hc    = Xf;   // safe alias: X only read by k_gemm, which precedes k_rnn

  hipLaunchKernelGGL(k_cvt,    dim3(12288), dim3(256), 0, stream, emb,  Xf, 25165824);
  hipLaunchKernelGGL(k_cvt,    dim3(384),   dim3(256), 0, stream, wihf, Wcat,          786432);
  hipLaunchKernelGGL(k_cvt,    dim3(384),   dim3(256), 0, stream, wihb, Wcat + 786432, 786432);
  hipLaunchKernelGGL(k_cvt,    dim3(3),     dim3(256), 0, stream, wprj, Wpj, 4608);
  hipLaunchKernelGGL(k_wpack7, dim3(128),   dim3(256), 0, stream, whhf, whhb, Wpack);
  hipLaunchKernelGGL(k_gemm,   dim3(4096),  dim3(256), 0, stream, Xf, Wcat, bfp, bbp, gx);
  hipLaunchKernelGGL(k_rnn,    dim3(128),   dim3(512), 0, stream, (const i32x4*)Wpack, gx, Hc);
  hipLaunchKernelGGL(k_emis,   dim3(8192),  dim3(256), 0, stream, Hc, Wpj, bprj, e);
  hipLaunchKernelGGL(k_crf,    dim3(64),    dim3(64),  0, stream, e, tags, mask, st, en, tr, llh);
  hipLaunchKernelGGL(k_red,    dim3(1),     dim3(64),  0, stream, llh, (float*)d_out);
}